// Round 16
// baseline (461.849 us; speedup 1.0000x reference)
//
#include <hip/hip_runtime.h>
#include <hip/hip_fp16.h>

#define FDIM 128
#define NCLS 16

#define SCAN_T 256
#define SCAN_I 8
#define SCAN_CHUNK (SCAN_T * SCAN_I)  // 2048 elements per block

typedef _Float16 f16x8 __attribute__((ext_vector_type(8)));
typedef float f32x4 __attribute__((ext_vector_type(4)));

// ---------------- CSR build ----------------
__global__ void k_count(const int* __restrict__ dst, int* cnt, int e) {
    int i = blockIdx.x * blockDim.x + threadIdx.x;
    if (i < e) atomicAdd(&cnt[dst[i]], 1);
}

// phase 1: block-local exclusive scan, per-block total; also computes dinv
__global__ __launch_bounds__(SCAN_T) void k_scan1(const int* __restrict__ cnt,
                                                  int* __restrict__ excl,
                                                  int* __restrict__ blockSum,
                                                  float* __restrict__ dinv, int n) {
    __shared__ int ts[SCAN_T];
    int b = blockIdx.x, t = threadIdx.x;
    int base = b * SCAN_CHUNK + t * SCAN_I;
    int v[SCAN_I];
    int s = 0;
    #pragma unroll
    for (int i = 0; i < SCAN_I; ++i) {
        int idx = base + i;
        v[i] = (idx < n) ? cnt[idx] : 0;
        if (idx < n) dinv[idx] = rsqrtf((float)(v[i] + 1));  // +1 self-loop
        s += v[i];
    }
    ts[t] = s;
    __syncthreads();
    for (int off = 1; off < SCAN_T; off <<= 1) {
        int x = (t >= off) ? ts[t - off] : 0;
        __syncthreads();
        ts[t] += x;
        __syncthreads();
    }
    int ex = (t == 0) ? 0 : ts[t - 1];
    #pragma unroll
    for (int i = 0; i < SCAN_I; ++i) {
        int idx = base + i;
        if (idx < n) excl[idx] = ex;
        ex += v[i];
    }
    if (t == SCAN_T - 1) blockSum[b] = ts[SCAN_T - 1];
}

// phase 2 (block 0) + W pre-transpose (blocks 1,2) in one launch
__global__ __launch_bounds__(1024) void k_scan2_prepw(int* blockSum, int* total, int nb,
                                                      const float* __restrict__ W1,
                                                      const float* __restrict__ W2,
                                                      __half* __restrict__ T1,
                                                      __half* __restrict__ T2) {
    if (blockIdx.x == 0) {
        __shared__ int ts[1024];
        int t = threadIdx.x;
        int v = (t < nb) ? blockSum[t] : 0;
        ts[t] = v;
        __syncthreads();
        for (int off = 1; off < 1024; off <<= 1) {
            int x = (t >= off) ? ts[t - off] : 0;
            __syncthreads();
            ts[t] += x;
            __syncthreads();
        }
        if (t < nb) blockSum[t] = (t == 0) ? 0 : ts[t - 1];
        if (t == 1023) *total = ts[1023];
    } else {
        const float* W = (blockIdx.x == 1) ? W1 : W2;
        __half* T = (blockIdx.x == 1) ? T1 : T2;
        for (int i = threadIdx.x; i < 128 * 32; i += 1024) {
            int c = i >> 5, k4 = (i & 31) * 4;  // output [c][k4..k4+3]
            float a = W[(k4 + 0) * 128 + c];
            float b = W[(k4 + 1) * 128 + c];
            float d = W[(k4 + 2) * 128 + c];
            float f = W[(k4 + 3) * 128 + c];
            __half2 h0 = __float22half2_rn(make_float2(a, b));
            __half2 h1 = __float22half2_rn(make_float2(d, f));
            uint2 u;
            u.x = *reinterpret_cast<unsigned int*>(&h0);
            u.y = *reinterpret_cast<unsigned int*>(&h1);
            *reinterpret_cast<uint2*>(&T[c * 128 + k4]) = u;
        }
    }
}

// phase 3: add block offsets, copy to cursor, write row_ptr[n]
__global__ void k_scan3(int* __restrict__ row_ptr, int* __restrict__ cursor,
                        const int* __restrict__ blockSum, const int* __restrict__ total,
                        int n) {
    int i = blockIdx.x * blockDim.x + threadIdx.x;
    if (i < n) {
        int v = row_ptr[i] + blockSum[i / SCAN_CHUNK];
        row_ptr[i] = v;
        cursor[i] = v;
    }
    if (i == 0) row_ptr[n] = *total;
}

// ------- MERGED: GEMM1 (blocks < bg) + scatter (blocks >= bg) -------
// Independent workloads: gemm1 needs dinv/x/wt1 (ready after scan1/scan2);
// scatter needs cursor (ready after scan3). Disjoint writes (bufA vs
// csr_off/cursor). Merging removes a dispatch boundary and overlaps
// scatter's random-atomic latency under MFMA/LDS work.
__global__ __launch_bounds__(512) void k_gemm1_scatter(
    const float* __restrict__ A, const __half* __restrict__ WT,
    const float* __restrict__ dinv, __half* __restrict__ C, int n, int bg,
    const int* __restrict__ src, const int* __restrict__ dst,
    int* cursor, int* __restrict__ csr_off, int e) {
    __shared__ _Float16 as[128 * 128];   // 32 KB  [r][k] swizzled
    __shared__ _Float16 wt[128 * 128];   // 32 KB  [c][k] swizzled

    if (blockIdx.x >= bg) {
        // ---- scatter path: store BYTE offset of fp16 source row (src*256) ----
        int i = (blockIdx.x - bg) * 512 + threadIdx.x;
        if (i < e) {
            int pos = atomicAdd(&cursor[dst[i]], 1);
            csr_off[pos] = src[i] << 8;
        }
        return;
    }

    // ---- GEMM1 path (fp32 input) ----
    int t = threadIdx.x;
    int r0 = blockIdx.x * 128;

    for (int i = t; i < 2048; i += 512) {
        int c = i >> 4, k8 = i & 15;
        uint4 u = reinterpret_cast<const uint4*>(WT)[i];
        int byte = (c * 256 + k8 * 16) ^ ((c & 7) << 4);
        *reinterpret_cast<uint4*>(reinterpret_cast<char*>(wt) + byte) = u;
    }
    for (int i = t; i < 128 * 16; i += 512) {
        int r = i >> 4, c8 = i & 15;
        float4 v0 = make_float4(0.f, 0.f, 0.f, 0.f);
        float4 v1 = make_float4(0.f, 0.f, 0.f, 0.f);
        if (r0 + r < n) {
            v0 = reinterpret_cast<const float4*>(A)[(size_t)(r0 + r) * 32 + c8 * 2];
            v1 = reinterpret_cast<const float4*>(A)[(size_t)(r0 + r) * 32 + c8 * 2 + 1];
        }
        __half2 h0 = __float22half2_rn(make_float2(v0.x, v0.y));
        __half2 h1 = __float22half2_rn(make_float2(v0.z, v0.w));
        __half2 h2 = __float22half2_rn(make_float2(v1.x, v1.y));
        __half2 h3 = __float22half2_rn(make_float2(v1.z, v1.w));
        uint4 u;
        u.x = *reinterpret_cast<unsigned int*>(&h0);
        u.y = *reinterpret_cast<unsigned int*>(&h1);
        u.z = *reinterpret_cast<unsigned int*>(&h2);
        u.w = *reinterpret_cast<unsigned int*>(&h3);
        int byte = (r * 256 + c8 * 16) ^ ((r & 7) << 4);
        *reinterpret_cast<uint4*>(reinterpret_cast<char*>(as) + byte) = u;
    }
    __syncthreads();

    int w = t >> 6, l = t & 63;
    int lrow = l & 15, lk = l >> 4;
    int rw = w * 16;

    f16x8 afrag[4];
    #pragma unroll
    for (int ks = 0; ks < 4; ++ks) {
        int row = rw + lrow;
        int byte = (row * 256 + (ks * 4 + lk) * 16) ^ ((row & 7) << 4);
        afrag[ks] = *reinterpret_cast<const f16x8*>(reinterpret_cast<const char*>(as) + byte);
    }
    float dv[4];
    #pragma unroll
    for (int reg = 0; reg < 4; ++reg) {
        int rg = r0 + rw + lk * 4 + reg;
        dv[reg] = (rg < n) ? dinv[rg] : 0.f;
    }

    #pragma unroll
    for (int ct = 0; ct < 8; ++ct) {
        f32x4 acc = {0.f, 0.f, 0.f, 0.f};
        #pragma unroll
        for (int ks = 0; ks < 4; ++ks) {
            int c = ct * 16 + lrow;
            int byte = (c * 256 + (ks * 4 + lk) * 16) ^ ((c & 7) << 4);
            f16x8 bfrag = *reinterpret_cast<const f16x8*>(reinterpret_cast<const char*>(wt) + byte);
            acc = __builtin_amdgcn_mfma_f32_16x16x32_f16(afrag[ks], bfrag, acc, 0, 0, 0);
        }
        #pragma unroll
        for (int reg = 0; reg < 4; ++reg) {
            int rg = r0 + rw + lk * 4 + reg;
            if (rg < n)
                C[(size_t)rg * FDIM + ct * 16 + lrow] = __float2half(acc[reg] * dv[reg]);
        }
    }
}

// ------- MFMA GEMM (layer 2, fp16 input) -------
__global__ __launch_bounds__(512) void k_gemm_mfma16(const __half* __restrict__ A,
                                                     const __half* __restrict__ WT,
                                                     const float* __restrict__ dinv,
                                                     __half* __restrict__ C, int n) {
    __shared__ _Float16 as[128 * 128];
    __shared__ _Float16 wt[128 * 128];
    int t = threadIdx.x;
    int r0 = blockIdx.x * 128;

    for (int i = t; i < 2048; i += 512) {
        int c = i >> 4, k8 = i & 15;
        uint4 u = reinterpret_cast<const uint4*>(WT)[i];
        int byte = (c * 256 + k8 * 16) ^ ((c & 7) << 4);
        *reinterpret_cast<uint4*>(reinterpret_cast<char*>(wt) + byte) = u;
    }
    for (int i = t; i < 128 * 16; i += 512) {
        int r = i >> 4, c8 = i & 15;
        uint4 u = make_uint4(0, 0, 0, 0);
        if (r0 + r < n)
            u = reinterpret_cast<const uint4*>(A)[(size_t)(r0 + r) * 16 + c8];
        int byte = (r * 256 + c8 * 16) ^ ((r & 7) << 4);
        *reinterpret_cast<uint4*>(reinterpret_cast<char*>(as) + byte) = u;
    }
    __syncthreads();

    int w = t >> 6, l = t & 63;
    int lrow = l & 15, lk = l >> 4;
    int rw = w * 16;

    f16x8 afrag[4];
    #pragma unroll
    for (int ks = 0; ks < 4; ++ks) {
        int row = rw + lrow;
        int byte = (row * 256 + (ks * 4 + lk) * 16) ^ ((row & 7) << 4);
        afrag[ks] = *reinterpret_cast<const f16x8*>(reinterpret_cast<const char*>(as) + byte);
    }
    float dv[4];
    #pragma unroll
    for (int reg = 0; reg < 4; ++reg) {
        int rg = r0 + rw + lk * 4 + reg;
        dv[reg] = (rg < n) ? dinv[rg] : 0.f;
    }

    #pragma unroll
    for (int ct = 0; ct < 8; ++ct) {
        f32x4 acc = {0.f, 0.f, 0.f, 0.f};
        #pragma unroll
        for (int ks = 0; ks < 4; ++ks) {
            int c = ct * 16 + lrow;
            int byte = (c * 256 + (ks * 4 + lk) * 16) ^ ((c & 7) << 4);
            f16x8 bfrag = *reinterpret_cast<const f16x8*>(reinterpret_cast<const char*>(wt) + byte);
            acc = __builtin_amdgcn_mfma_f32_16x16x32_f16(afrag[ks], bfrag, acc, 0, 0, 0);
        }
        #pragma unroll
        for (int reg = 0; reg < 4; ++reg) {
            int rg = r0 + rw + lk * 4 + reg;
            if (rg < n)
                C[(size_t)rg * FDIM + ct * 16 + lrow] = __float2half(acc[reg] * dv[reg]);
        }
    }
}

// -------- aggregation (both layers): V2 inner loop, 2 edges per dwordx2 load --------
// R13/R15-proven 141 us floor. readlane (SALU) + cndmask; fp16 depth-2 trees, f32 accum.
template <bool FUSE>
__global__ __launch_bounds__(256) void k_agg2e(const __half* __restrict__ Y,
                                               const int* __restrict__ csr_off,
                                               const int* __restrict__ row_ptr,
                                               const float* __restrict__ dinv,
                                               const float* __restrict__ bias,
                                               const float* __restrict__ Wl,
                                               const float* __restrict__ bl,
                                               __half* __restrict__ hout,
                                               float* __restrict__ out, int n) {
    __shared__ float s_wl[NCLS * FDIM];  // transposed: [c][k]
    __shared__ float s_bl[NCLS];
    if (FUSE) {
        for (int i = threadIdx.x; i < FDIM * NCLS / 4; i += 256) {
            int k = i >> 2, c4 = (i & 3) * 4;
            float4 v = reinterpret_cast<const float4*>(Wl)[i];
            s_wl[(c4 + 0) * FDIM + k] = v.x;
            s_wl[(c4 + 1) * FDIM + k] = v.y;
            s_wl[(c4 + 2) * FDIM + k] = v.z;
            s_wl[(c4 + 3) * FDIM + k] = v.w;
        }
        if (threadIdx.x < NCLS) s_bl[threadIdx.x] = bl[threadIdx.x];
        __syncthreads();
    }

    int node = blockIdx.x * 4 + (threadIdx.x >> 6);
    if (node >= n) return;
    int lane = threadIdx.x & 63;
    int half = lane >> 5, l32 = lane & 31;
    const char* Yb = reinterpret_cast<const char*>(Y);
    const char* lanebase = Yb + (l32 << 3);  // loop-invariant

    float a0 = 0.f, a1 = 0.f, a2 = 0.f, a3 = 0.f;
    int beg = row_ptr[node], end = row_ptr[node + 1];

    for (int j0 = beg; j0 < end; j0 += 64) {
        int cnt = min(64, end - j0);
        int myoff = (j0 + lane < end) ? csr_off[j0 + lane] : 0;
        int k = 0;
        for (; k + 8 <= cnt; k += 8) {
            uint2 u[4];
            #pragma unroll
            for (int i = 0; i < 4; ++i) {
                int oe = __builtin_amdgcn_readlane(myoff, k + 2 * i);
                int oo = __builtin_amdgcn_readlane(myoff, k + 2 * i + 1);
                int off = half ? oo : oe;
                u[i] = *reinterpret_cast<const uint2*>(lanebase + off);
            }
            __half2* p = reinterpret_cast<__half2*>(u);
            __half2 lo = __hadd2(__hadd2(p[0], p[2]), __hadd2(p[4], p[6]));
            __half2 hi = __hadd2(__hadd2(p[1], p[3]), __hadd2(p[5], p[7]));
            float2 flo = __half22float2(lo), fhi = __half22float2(hi);
            a0 += flo.x; a1 += flo.y; a2 += fhi.x; a3 += fhi.y;
        }
        for (; k + 2 <= cnt; k += 2) {
            int oe = __builtin_amdgcn_readlane(myoff, k);
            int oo = __builtin_amdgcn_readlane(myoff, k + 1);
            int off = half ? oo : oe;
            uint2 u = *reinterpret_cast<const uint2*>(lanebase + off);
            __half2* p = reinterpret_cast<__half2*>(&u);
            float2 flo = __half22float2(p[0]), fhi = __half22float2(p[1]);
            a0 += flo.x; a1 += flo.y; a2 += fhi.x; a3 += fhi.y;
        }
        if (k < cnt) {  // odd leftover: only half 0 contributes
            int o = __builtin_amdgcn_readlane(myoff, k);
            uint2 u = *reinterpret_cast<const uint2*>(lanebase + o);
            __half2* p = reinterpret_cast<__half2*>(&u);
            float sel = (half == 0) ? 1.0f : 0.0f;
            float2 flo = __half22float2(p[0]), fhi = __half22float2(p[1]);
            a0 += flo.x * sel; a1 += flo.y * sel;
            a2 += fhi.x * sel; a3 += fhi.y * sel;
        }
    }

    a0 += __shfl_xor(a0, 32, 64);
    a1 += __shfl_xor(a1, 32, 64);
    a2 += __shfl_xor(a2, 32, 64);
    a3 += __shfl_xor(a3, 32, 64);

    // self term (after half-combine: each half's copy gets it exactly once)
    uint2 su = *reinterpret_cast<const uint2*>(Yb + ((size_t)node << 8) + (l32 << 3));
    __half2* sp = reinterpret_cast<__half2*>(&su);
    float2 slo = __half22float2(sp[0]), shi = __half22float2(sp[1]);
    a0 += slo.x; a1 += slo.y; a2 += shi.x; a3 += shi.y;

    float di = dinv[node];
    float4 b = *reinterpret_cast<const float4*>(bias + l32 * 4);
    float h0 = fmaxf(a0 * di + b.x, 0.f);
    float h1 = fmaxf(a1 * di + b.y, 0.f);
    float h2 = fmaxf(a2 * di + b.z, 0.f);
    float h3 = fmaxf(a3 * di + b.w, 0.f);

    if (!FUSE) {
        if (half == 0) {
            __half2 o0 = __float22half2_rn(make_float2(h0, h1));
            __half2 o1 = __float22half2_rn(make_float2(h2, h3));
            uint2 o;
            o.x = *reinterpret_cast<unsigned int*>(&o0);
            o.y = *reinterpret_cast<unsigned int*>(&o1);
            *reinterpret_cast<uint2*>(reinterpret_cast<char*>(hout) + ((size_t)node << 8) + (l32 << 3)) = o;
        }
    } else {
        // per-lane partial logits over this lane's 4 h components (cols 4*l32..+3)
        float lg[NCLS];
        #pragma unroll
        for (int c = 0; c < NCLS; ++c) {
            float4 w4 = *reinterpret_cast<const float4*>(&s_wl[c * FDIM + l32 * 4]);
            lg[c] = h0 * w4.x + h1 * w4.y + h2 * w4.z + h3 * w4.w;
        }
        // butterfly within each 32-lane half (halves identical afterwards)
        #pragma unroll
        for (int off = 1; off < 32; off <<= 1) {
            #pragma unroll
            for (int c = 0; c < NCLS; ++c) lg[c] += __shfl_xor(lg[c], off, 64);
        }
        #pragma unroll
        for (int c = 0; c < NCLS; ++c) lg[c] += s_bl[c];
        float m = lg[0];
        #pragma unroll
        for (int c = 1; c < NCLS; ++c) m = fmaxf(m, lg[c]);
        float ev[NCLS];
        float sum = 0.f;
        #pragma unroll
        for (int c = 0; c < NCLS; ++c) { ev[c] = __expf(lg[c] - m); sum += ev[c]; }
        float inv = 1.0f / sum;
        float mye = 0.f;
        #pragma unroll
        for (int c = 0; c < NCLS; ++c) if (lane == c) mye = ev[c];  // static idx
        if (lane < NCLS) out[(size_t)node * NCLS + lane] = mye * inv;
    }
}

extern "C" void kernel_launch(void* const* d_in, const int* in_sizes, int n_in,
                              void* d_out, int out_size, void* d_ws, size_t ws_size,
                              hipStream_t stream) {
    const float* x  = (const float*)d_in[0];
    const int*   ei = (const int*)d_in[1];
    const float* W1 = (const float*)d_in[2];
    const float* b1 = (const float*)d_in[3];
    const float* W2 = (const float*)d_in[4];
    const float* b2 = (const float*)d_in[5];
    const float* Wl = (const float*)d_in[6];
    const float* bl = (const float*)d_in[7];
    float* out = (float*)d_out;

    int n = in_sizes[0] / FDIM;
    int e = in_sizes[1] / 2;
    const int* src = ei;
    const int* dst = ei + e;

    int nb = (n + SCAN_CHUNK - 1) / SCAN_CHUNK;  // <=1024

    // workspace layout (R11/R13-proven)
    float* dinv    = (float*)d_ws;                     // n
    int*   cnt     = (int*)(dinv + n);                 // n
    int*   row_ptr = cnt + n;                          // n+1
    int*   cursor  = row_ptr + n + 1;                  // n
    int*   blockSum= cursor + n;                       // nb (<=1024)
    int*   total   = blockSum + 1024;                  // 1
    int*   csr_off = total + 1;                        // e
    uintptr_t p = (uintptr_t)(csr_off + e);
    p = (p + 15) & ~(uintptr_t)15;
    __half* wt1 = (__half*)p;                          // 128*128
    __half* wt2 = wt1 + 128 * 128;                     // 128*128
    __half* bufA = wt2 + 128 * 128;                    // n*128 halves
    __half* bufB = bufA + (size_t)n * FDIM;            // n*128 halves

    int bn = (n + 255) / 256;
    int be = (e + 255) / 256;

    // CSR + norms + weight prep
    hipMemsetAsync(cnt, 0, (size_t)n * sizeof(int), stream);
    k_count<<<be, 256, 0, stream>>>(dst, cnt, e);
    k_scan1<<<nb, SCAN_T, 0, stream>>>(cnt, row_ptr, blockSum, dinv, n);
    k_scan2_prepw<<<3, 1024, 0, stream>>>(blockSum, total, nb, W1, W2, wt1, wt2);
    k_scan3<<<bn, 256, 0, stream>>>(row_ptr, cursor, blockSum, total, n);

    int bg = (n + 127) / 128;
    int bs = (e + 511) / 512;
    int ba = (n + 3) / 4;

    // layer 1 GEMM + edge scatter merged (independent; disjoint writes)
    k_gemm1_scatter<<<bg + bs, 512, 0, stream>>>(x, wt1, dinv, bufA, n, bg,
                                                 src, dst, cursor, csr_off, e);
    k_agg2e<false><<<ba, 256, 0, stream>>>(bufA, csr_off, row_ptr, dinv, b1, Wl, bl, bufB, out, n);

    // layer 2 (+ fused classifier/softmax)
    k_gemm_mfma16<<<bg, 512, 0, stream>>>(bufB, wt2, dinv, bufA, n);
    k_agg2e<true><<<ba, 256, 0, stream>>>(bufA, csr_off, row_ptr, dinv, b2, Wl, bl, bufB, out, n);
}

// Round 17
// 420.145 us; speedup vs baseline: 1.0993x; 1.0993x over previous
//
#include <hip/hip_runtime.h>
#include <hip/hip_fp16.h>

#define FDIM 128
#define NCLS 16

#define SCAN_T 256
#define SCAN_I 8
#define SCAN_CHUNK (SCAN_T * SCAN_I)  // 2048 elements per block

#define EPB 4096        // edges per k_bucket block
#define MAXBUK 64

typedef _Float16 f16x8 __attribute__((ext_vector_type(8)));
typedef float f32x4 __attribute__((ext_vector_type(4)));

// ---------------- CSR build ----------------
__global__ void k_count(const int* __restrict__ dst, int* cnt, int e) {
    int i = blockIdx.x * blockDim.x + threadIdx.x;
    if (i < e) atomicAdd(&cnt[dst[i]], 1);
}

// phase 1: block-local exclusive scan, per-block total; also computes dinv
__global__ __launch_bounds__(SCAN_T) void k_scan1(const int* __restrict__ cnt,
                                                  int* __restrict__ excl,
                                                  int* __restrict__ blockSum,
                                                  float* __restrict__ dinv, int n) {
    __shared__ int ts[SCAN_T];
    int b = blockIdx.x, t = threadIdx.x;
    int base = b * SCAN_CHUNK + t * SCAN_I;
    int v[SCAN_I];
    int s = 0;
    #pragma unroll
    for (int i = 0; i < SCAN_I; ++i) {
        int idx = base + i;
        v[i] = (idx < n) ? cnt[idx] : 0;
        if (idx < n) dinv[idx] = rsqrtf((float)(v[i] + 1));  // +1 self-loop
        s += v[i];
    }
    ts[t] = s;
    __syncthreads();
    for (int off = 1; off < SCAN_T; off <<= 1) {
        int x = (t >= off) ? ts[t - off] : 0;
        __syncthreads();
        ts[t] += x;
        __syncthreads();
    }
    int ex = (t == 0) ? 0 : ts[t - 1];
    #pragma unroll
    for (int i = 0; i < SCAN_I; ++i) {
        int idx = base + i;
        if (idx < n) excl[idx] = ex;
        ex += v[i];
    }
    if (t == SCAN_T - 1) blockSum[b] = ts[SCAN_T - 1];
}

// phase 2 (block 0) + W pre-transpose (blocks 1,2) in one launch
__global__ __launch_bounds__(1024) void k_scan2_prepw(int* blockSum, int* total, int nb,
                                                      const float* __restrict__ W1,
                                                      const float* __restrict__ W2,
                                                      __half* __restrict__ T1,
                                                      __half* __restrict__ T2) {
    if (blockIdx.x == 0) {
        __shared__ int ts[1024];
        int t = threadIdx.x;
        int v = (t < nb) ? blockSum[t] : 0;
        ts[t] = v;
        __syncthreads();
        for (int off = 1; off < 1024; off <<= 1) {
            int x = (t >= off) ? ts[t - off] : 0;
            __syncthreads();
            ts[t] += x;
            __syncthreads();
        }
        if (t < nb) blockSum[t] = (t == 0) ? 0 : ts[t - 1];
        if (t == 1023) *total = ts[1023];
    } else {
        const float* W = (blockIdx.x == 1) ? W1 : W2;
        __half* T = (blockIdx.x == 1) ? T1 : T2;
        for (int i = threadIdx.x; i < 128 * 32; i += 1024) {
            int c = i >> 5, k4 = (i & 31) * 4;  // output [c][k4..k4+3]
            float a = W[(k4 + 0) * 128 + c];
            float b = W[(k4 + 1) * 128 + c];
            float d = W[(k4 + 2) * 128 + c];
            float f = W[(k4 + 3) * 128 + c];
            __half2 h0 = __float22half2_rn(make_float2(a, b));
            __half2 h1 = __float22half2_rn(make_float2(d, f));
            uint2 u;
            u.x = *reinterpret_cast<unsigned int*>(&h0);
            u.y = *reinterpret_cast<unsigned int*>(&h1);
            *reinterpret_cast<uint2*>(&T[c * 128 + k4]) = u;
        }
    }
}

// phase 3: add block offsets, copy to cursor, write row_ptr[n]; init bucket cursors
__global__ void k_scan3(int* __restrict__ row_ptr, int* __restrict__ cursor,
                        const int* __restrict__ blockSum, const int* __restrict__ total,
                        int* __restrict__ bcur, int shift, int n) {
    int i = blockIdx.x * blockDim.x + threadIdx.x;
    if (i < n) {
        int v = row_ptr[i] + blockSum[i / SCAN_CHUNK];
        row_ptr[i] = v;
        cursor[i] = v;
        if ((i & ((1 << shift) - 1)) == 0) bcur[i >> shift] = v;  // bucket base
    }
    if (i == 0) row_ptr[n] = *total;
}

// -------- scatter pass 1: bucket edges (dst>>shift) into bucket-major pairs --------
// LDS slab staging so all global writes are coalesced multi-sector runs.
__global__ __launch_bounds__(512) void k_bucket(const int* __restrict__ src,
                                                const int* __restrict__ dst,
                                                int* bcur, uint2* __restrict__ pairs,
                                                int e, int shift, int nbuk) {
    __shared__ int hist[MAXBUK], lhist[MAXBUK], base[MAXBUK], lpre[MAXBUK];
    __shared__ uint2 slab[EPB];        // 32 KB
    __shared__ unsigned char bkt[EPB]; // 4 KB
    int t = threadIdx.x;
    int e0 = blockIdx.x * EPB;
    int cntE = min(EPB, e - e0);

    if (t < nbuk) { hist[t] = 0; lhist[t] = 0; }
    __syncthreads();

    // count
    for (int k = t; k < cntE; k += 512) {
        int b = dst[e0 + k] >> shift;
        atomicAdd(&hist[b], 1);
    }
    __syncthreads();

    // global base per bucket + exclusive prefix of hist (block-local)
    if (t < nbuk) base[t] = atomicAdd(&bcur[t], hist[t]);
    if (t == 0) {
        int acc = 0;
        for (int b = 0; b < nbuk; ++b) { lpre[b] = acc; acc += hist[b]; }
    }
    __syncthreads();

    // place into slab bucket-ordered
    for (int k = t; k < cntE; k += 512) {
        int d = dst[e0 + k];
        int s = src[e0 + k];
        int b = d >> shift;
        int r = atomicAdd(&lhist[b], 1);
        int j = lpre[b] + r;
        slab[j] = make_uint2((unsigned)(s << 8), (unsigned)d);
        bkt[j] = (unsigned char)b;
    }
    __syncthreads();

    // flush: consecutive j within a bucket -> consecutive global dest (coalesced runs)
    for (int j = t; j < cntE; j += 512) {
        int b = bkt[j];
        pairs[base[b] + (j - lpre[b])] = slab[j];
    }
}

// -------- scatter pass 2: fine scatter within L2-resident bucket windows --------
__global__ void k_fine(const uint2* __restrict__ pairs, int* cursor,
                       int* __restrict__ csr_off, int e) {
    int i = blockIdx.x * blockDim.x + threadIdx.x;
    if (i >= e) return;
    uint2 up = pairs[i];
    int pos = atomicAdd(&cursor[up.y], 1);
    csr_off[pos] = (int)up.x;
}

// ------- MFMA GEMM: Y[n,128](fp16) = (A[n,128] @ W[128,128]) * dinv[row] -------
template <typename T>
__global__ __launch_bounds__(512) void k_gemm_mfma(const T* __restrict__ A,
                                                   const __half* __restrict__ WT,
                                                   const float* __restrict__ dinv,
                                                   __half* __restrict__ C, int n) {
    __shared__ _Float16 as[128 * 128];   // 32 KB  [r][k] swizzled
    __shared__ _Float16 wt[128 * 128];   // 32 KB  [c][k] swizzled
    int t = threadIdx.x;
    int r0 = blockIdx.x * 128;

    for (int i = t; i < 2048; i += 512) {
        int c = i >> 4, k8 = i & 15;
        uint4 u = reinterpret_cast<const uint4*>(WT)[i];
        int byte = (c * 256 + k8 * 16) ^ ((c & 7) << 4);
        *reinterpret_cast<uint4*>(reinterpret_cast<char*>(wt) + byte) = u;
    }

    if constexpr (sizeof(T) == 4) {
        for (int i = t; i < 128 * 16; i += 512) {
            int r = i >> 4, c8 = i & 15;
            float4 v0 = make_float4(0.f, 0.f, 0.f, 0.f);
            float4 v1 = make_float4(0.f, 0.f, 0.f, 0.f);
            if (r0 + r < n) {
                v0 = reinterpret_cast<const float4*>(A)[(size_t)(r0 + r) * 32 + c8 * 2];
                v1 = reinterpret_cast<const float4*>(A)[(size_t)(r0 + r) * 32 + c8 * 2 + 1];
            }
            __half2 h0 = __float22half2_rn(make_float2(v0.x, v0.y));
            __half2 h1 = __float22half2_rn(make_float2(v0.z, v0.w));
            __half2 h2 = __float22half2_rn(make_float2(v1.x, v1.y));
            __half2 h3 = __float22half2_rn(make_float2(v1.z, v1.w));
            uint4 u;
            u.x = *reinterpret_cast<unsigned int*>(&h0);
            u.y = *reinterpret_cast<unsigned int*>(&h1);
            u.z = *reinterpret_cast<unsigned int*>(&h2);
            u.w = *reinterpret_cast<unsigned int*>(&h3);
            int byte = (r * 256 + c8 * 16) ^ ((r & 7) << 4);
            *reinterpret_cast<uint4*>(reinterpret_cast<char*>(as) + byte) = u;
        }
    } else {
        for (int i = t; i < 128 * 16; i += 512) {
            int r = i >> 4, c8 = i & 15;
            uint4 u = make_uint4(0, 0, 0, 0);
            if (r0 + r < n)
                u = reinterpret_cast<const uint4*>(A)[(size_t)(r0 + r) * 16 + c8];
            int byte = (r * 256 + c8 * 16) ^ ((r & 7) << 4);
            *reinterpret_cast<uint4*>(reinterpret_cast<char*>(as) + byte) = u;
        }
    }
    __syncthreads();

    int w = t >> 6, l = t & 63;
    int lrow = l & 15, lk = l >> 4;
    int rw = w * 16;

    f16x8 afrag[4];
    #pragma unroll
    for (int ks = 0; ks < 4; ++ks) {
        int row = rw + lrow;
        int byte = (row * 256 + (ks * 4 + lk) * 16) ^ ((row & 7) << 4);
        afrag[ks] = *reinterpret_cast<const f16x8*>(reinterpret_cast<const char*>(as) + byte);
    }
    float dv[4];
    #pragma unroll
    for (int reg = 0; reg < 4; ++reg) {
        int rg = r0 + rw + lk * 4 + reg;
        dv[reg] = (rg < n) ? dinv[rg] : 0.f;
    }

    #pragma unroll
    for (int ct = 0; ct < 8; ++ct) {
        f32x4 acc = {0.f, 0.f, 0.f, 0.f};
        #pragma unroll
        for (int ks = 0; ks < 4; ++ks) {
            int c = ct * 16 + lrow;
            int byte = (c * 256 + (ks * 4 + lk) * 16) ^ ((c & 7) << 4);
            f16x8 bfrag = *reinterpret_cast<const f16x8*>(reinterpret_cast<const char*>(wt) + byte);
            acc = __builtin_amdgcn_mfma_f32_16x16x32_f16(afrag[ks], bfrag, acc, 0, 0, 0);
        }
        #pragma unroll
        for (int reg = 0; reg < 4; ++reg) {
            int rg = r0 + rw + lk * 4 + reg;
            if (rg < n)
                C[(size_t)rg * FDIM + ct * 16 + lrow] = __float2half(acc[reg] * dv[reg]);
        }
    }
}

// -------- aggregation (both layers): V2 inner loop, 2 edges per dwordx2 load --------
// R13/R15-proven 141 us floor. readlane (SALU) + cndmask; fp16 depth-2 trees, f32 accum.
template <bool FUSE>
__global__ __launch_bounds__(256) void k_agg2e(const __half* __restrict__ Y,
                                               const int* __restrict__ csr_off,
                                               const int* __restrict__ row_ptr,
                                               const float* __restrict__ dinv,
                                               const float* __restrict__ bias,
                                               const float* __restrict__ Wl,
                                               const float* __restrict__ bl,
                                               __half* __restrict__ hout,
                                               float* __restrict__ out, int n) {
    __shared__ float s_wl[NCLS * FDIM];  // transposed: [c][k]
    __shared__ float s_bl[NCLS];
    if (FUSE) {
        for (int i = threadIdx.x; i < FDIM * NCLS / 4; i += 256) {
            int k = i >> 2, c4 = (i & 3) * 4;
            float4 v = reinterpret_cast<const float4*>(Wl)[i];
            s_wl[(c4 + 0) * FDIM + k] = v.x;
            s_wl[(c4 + 1) * FDIM + k] = v.y;
            s_wl[(c4 + 2) * FDIM + k] = v.z;
            s_wl[(c4 + 3) * FDIM + k] = v.w;
        }
        if (threadIdx.x < NCLS) s_bl[threadIdx.x] = bl[threadIdx.x];
        __syncthreads();
    }

    int node = blockIdx.x * 4 + (threadIdx.x >> 6);
    if (node >= n) return;
    int lane = threadIdx.x & 63;
    int half = lane >> 5, l32 = lane & 31;
    const char* Yb = reinterpret_cast<const char*>(Y);
    const char* lanebase = Yb + (l32 << 3);  // loop-invariant

    float a0 = 0.f, a1 = 0.f, a2 = 0.f, a3 = 0.f;
    int beg = row_ptr[node], end = row_ptr[node + 1];

    for (int j0 = beg; j0 < end; j0 += 64) {
        int cnt = min(64, end - j0);
        int myoff = (j0 + lane < end) ? csr_off[j0 + lane] : 0;
        int k = 0;
        for (; k + 8 <= cnt; k += 8) {
            uint2 u[4];
            #pragma unroll
            for (int i = 0; i < 4; ++i) {
                int oe = __builtin_amdgcn_readlane(myoff, k + 2 * i);
                int oo = __builtin_amdgcn_readlane(myoff, k + 2 * i + 1);
                int off = half ? oo : oe;
                u[i] = *reinterpret_cast<const uint2*>(lanebase + off);
            }
            __half2* p = reinterpret_cast<__half2*>(u);
            __half2 lo = __hadd2(__hadd2(p[0], p[2]), __hadd2(p[4], p[6]));
            __half2 hi = __hadd2(__hadd2(p[1], p[3]), __hadd2(p[5], p[7]));
            float2 flo = __half22float2(lo), fhi = __half22float2(hi);
            a0 += flo.x; a1 += flo.y; a2 += fhi.x; a3 += fhi.y;
        }
        for (; k + 2 <= cnt; k += 2) {
            int oe = __builtin_amdgcn_readlane(myoff, k);
            int oo = __builtin_amdgcn_readlane(myoff, k + 1);
            int off = half ? oo : oe;
            uint2 u = *reinterpret_cast<const uint2*>(lanebase + off);
            __half2* p = reinterpret_cast<__half2*>(&u);
            float2 flo = __half22float2(p[0]), fhi = __half22float2(p[1]);
            a0 += flo.x; a1 += flo.y; a2 += fhi.x; a3 += fhi.y;
        }
        if (k < cnt) {  // odd leftover: only half 0 contributes
            int o = __builtin_amdgcn_readlane(myoff, k);
            uint2 u = *reinterpret_cast<const uint2*>(lanebase + o);
            __half2* p = reinterpret_cast<__half2*>(&u);
            float sel = (half == 0) ? 1.0f : 0.0f;
            float2 flo = __half22float2(p[0]), fhi = __half22float2(p[1]);
            a0 += flo.x * sel; a1 += flo.y * sel;
            a2 += fhi.x * sel; a3 += fhi.y * sel;
        }
    }

    a0 += __shfl_xor(a0, 32, 64);
    a1 += __shfl_xor(a1, 32, 64);
    a2 += __shfl_xor(a2, 32, 64);
    a3 += __shfl_xor(a3, 32, 64);

    // self term (after half-combine: each half's copy gets it exactly once)
    uint2 su = *reinterpret_cast<const uint2*>(Yb + ((size_t)node << 8) + (l32 << 3));
    __half2* sp = reinterpret_cast<__half2*>(&su);
    float2 slo = __half22float2(sp[0]), shi = __half22float2(sp[1]);
    a0 += slo.x; a1 += slo.y; a2 += shi.x; a3 += shi.y;

    float di = dinv[node];
    float4 b = *reinterpret_cast<const float4*>(bias + l32 * 4);
    float h0 = fmaxf(a0 * di + b.x, 0.f);
    float h1 = fmaxf(a1 * di + b.y, 0.f);
    float h2 = fmaxf(a2 * di + b.z, 0.f);
    float h3 = fmaxf(a3 * di + b.w, 0.f);

    if (!FUSE) {
        if (half == 0) {
            __half2 o0 = __float22half2_rn(make_float2(h0, h1));
            __half2 o1 = __float22half2_rn(make_float2(h2, h3));
            uint2 o;
            o.x = *reinterpret_cast<unsigned int*>(&o0);
            o.y = *reinterpret_cast<unsigned int*>(&o1);
            *reinterpret_cast<uint2*>(reinterpret_cast<char*>(hout) + ((size_t)node << 8) + (l32 << 3)) = o;
        }
    } else {
        // per-lane partial logits over this lane's 4 h components (cols 4*l32..+3)
        float lg[NCLS];
        #pragma unroll
        for (int c = 0; c < NCLS; ++c) {
            float4 w4 = *reinterpret_cast<const float4*>(&s_wl[c * FDIM + l32 * 4]);
            lg[c] = h0 * w4.x + h1 * w4.y + h2 * w4.z + h3 * w4.w;
        }
        // butterfly within each 32-lane half (halves identical afterwards)
        #pragma unroll
        for (int off = 1; off < 32; off <<= 1) {
            #pragma unroll
            for (int c = 0; c < NCLS; ++c) lg[c] += __shfl_xor(lg[c], off, 64);
        }
        #pragma unroll
        for (int c = 0; c < NCLS; ++c) lg[c] += s_bl[c];
        float m = lg[0];
        #pragma unroll
        for (int c = 1; c < NCLS; ++c) m = fmaxf(m, lg[c]);
        float ev[NCLS];
        float sum = 0.f;
        #pragma unroll
        for (int c = 0; c < NCLS; ++c) { ev[c] = __expf(lg[c] - m); sum += ev[c]; }
        float inv = 1.0f / sum;
        float mye = 0.f;
        #pragma unroll
        for (int c = 0; c < NCLS; ++c) if (lane == c) mye = ev[c];  // static idx
        if (lane < NCLS) out[(size_t)node * NCLS + lane] = mye * inv;
    }
}

extern "C" void kernel_launch(void* const* d_in, const int* in_sizes, int n_in,
                              void* d_out, int out_size, void* d_ws, size_t ws_size,
                              hipStream_t stream) {
    const float* x  = (const float*)d_in[0];
    const int*   ei = (const int*)d_in[1];
    const float* W1 = (const float*)d_in[2];
    const float* b1 = (const float*)d_in[3];
    const float* W2 = (const float*)d_in[4];
    const float* b2 = (const float*)d_in[5];
    const float* Wl = (const float*)d_in[6];
    const float* bl = (const float*)d_in[7];
    float* out = (float*)d_out;

    int n = in_sizes[0] / FDIM;
    int e = in_sizes[1] / 2;
    const int* src = ei;
    const int* dst = ei + e;

    int nb = (n + SCAN_CHUNK - 1) / SCAN_CHUNK;  // <=1024

    // bucket shift: <=64 buckets
    int shift = 11;
    while (((n + (1 << shift) - 1) >> shift) > MAXBUK) ++shift;
    int nbuk = (n + (1 << shift) - 1) >> shift;

    // workspace layout
    float* dinv    = (float*)d_ws;                     // n
    int*   cnt     = (int*)(dinv + n);                 // n
    int*   row_ptr = cnt + n;                          // n+1
    int*   cursor  = row_ptr + n + 1;                  // n
    int*   blockSum= cursor + n;                       // nb (<=1024)
    int*   total   = blockSum + 1024;                  // 1
    int*   bcur    = total + 1;                        // MAXBUK
    int*   csr_off = bcur + MAXBUK;                    // e
    uintptr_t p = (uintptr_t)(csr_off + e);
    p = (p + 15) & ~(uintptr_t)15;
    uint2* pairs = (uint2*)p;                          // e (12.8 MB)
    __half* wt1 = (__half*)(pairs + e);                // 128*128
    __half* wt2 = wt1 + 128 * 128;                     // 128*128
    __half* bufA = wt2 + 128 * 128;                    // n*128 halves
    __half* bufB = bufA + (size_t)n * FDIM;            // n*128 halves

    int bn = (n + 255) / 256;
    int be = (e + 255) / 256;

    // CSR + norms + weight prep
    hipMemsetAsync(cnt, 0, (size_t)n * sizeof(int), stream);
    k_count<<<be, 256, 0, stream>>>(dst, cnt, e);
    k_scan1<<<nb, SCAN_T, 0, stream>>>(cnt, row_ptr, blockSum, dinv, n);
    k_scan2_prepw<<<3, 1024, 0, stream>>>(blockSum, total, nb, W1, W2, wt1, wt2);
    k_scan3<<<bn, 256, 0, stream>>>(row_ptr, cursor, blockSum, total, bcur, shift, n);

    // 2-pass bucketed scatter
    int bbk = (e + EPB - 1) / EPB;
    k_bucket<<<bbk, 512, 0, stream>>>(src, dst, bcur, pairs, e, shift, nbuk);
    k_fine<<<be, 256, 0, stream>>>(pairs, cursor, csr_off, e);

    int bg = (n + 127) / 128;
    int ba = (n + 3) / 4;

    // layer 1
    k_gemm_mfma<float><<<bg, 512, 0, stream>>>(x, wt1, dinv, bufA, n);
    k_agg2e<false><<<ba, 256, 0, stream>>>(bufA, csr_off, row_ptr, dinv, b1, Wl, bl, bufB, out, n);

    // layer 2 (+ fused classifier/softmax)
    k_gemm_mfma<__half><<<bg, 512, 0, stream>>>(bufB, wt2, dinv, bufA, n);
    k_agg2e<true><<<ba, 256, 0, stream>>>(bufA, csr_off, row_ptr, dinv, b2, Wl, bl, bufB, out, n);
}